// Round 12
// baseline (6139.055 us; speedup 1.0000x reference)
//
#include <hip/hip_runtime.h>
#include <cmath>

#define NANCH 22500

// out layout offsets (floats)
#define OUT_REG   0
#define OUT_CLS   720000
#define OUT_ROIS  1080000
#define OUT_ROIID 1089600
#define OUT_ANCH  1092000

__device__ __forceinline__ unsigned keyOf(float f) {
  unsigned u = __float_as_uint(f);
  return (u & 0x80000000u) ? ~u : (u | 0x80000000u);
}

// correctly-rounded f32 exp: f64 exp then round once (glibc expf-equivalent)
__device__ __forceinline__ float cr_expf(float x) {
  return (float)exp((double)x);
}

// anchors: bit-match np _anchor_base (f64 math, f32 cast) + f32 shift add
__device__ __forceinline__ void anchor4(int a, int yy, int xx,
    float& y1, float& x1, float& y2, float& x2) {
  int ri = a / 3, si = a - ri * 3;
  double r = (ri == 0) ? 0.5 : ((ri == 1) ? 1.0 : 2.0);
  double s = (si == 0) ? 8.0 : ((si == 1) ? 16.0 : 32.0);
  double h = 16.0 * s * sqrt(r);
  double w = 16.0 * s * sqrt(1.0 / r);
  float sy = (float)(yy * 16), sx = (float)(xx * 16);
  y1 = sy + (float)(8.0 - 0.5 * h);
  x1 = sx + (float)(8.0 - 0.5 * w);
  y2 = sy + (float)(8.0 + 0.5 * h);
  x2 = sx + (float)(8.0 + 0.5 * w);
}

// ---------------- conv3x3 512->512 + bias + relu (f64 accumulate -> f32 round) ----------------
__global__ __launch_bounds__(256) void k_conv3x3(
    const float* __restrict__ x, const float* __restrict__ Wsh,
    const float* __restrict__ bsh, double* __restrict__ sh)
{
#pragma clang fp contract(off)
  __shared__ float xs[16 * 5 * 52];   // [ci16][row5][col52] halo-padded
  __shared__ float wl[144 * 64];      // [(ci*9+tap)][co64]
  const int t = threadIdx.x;
  const int p0 = blockIdx.x * 64, co0 = blockIdx.y * 64, b = blockIdx.z;
  const int pxg = t & 15, cog = t >> 4;
  const int r0 = p0 / 50;
  int off[4], pp[4];
  #pragma unroll
  for (int j = 0; j < 4; ++j) {
    int p = p0 + pxg * 4 + j;
    pp[j] = p;
    int r = p / 50, c = p - r * 50;
    off[j] = (r - r0 + 1) * 52 + c + 1;
  }
  double acc[4][4];
  #pragma unroll
  for (int j = 0; j < 4; ++j)
    #pragma unroll
    for (int i = 0; i < 4; ++i) acc[j][i] = 0.0;

  for (int cc = 0; cc < 32; ++cc) {
    const int cibase = cc * 16;
    for (int idx = t; idx < 16 * 260; idx += 256) {
      int ci = idx / 260;
      int rem = idx - ci * 260;
      int rr = rem / 52, cs = rem - rr * 52;
      int gr = r0 - 1 + rr, gc = cs - 1;
      float v = 0.f;
      if (gr >= 0 && gr < 50 && gc >= 0 && gc < 50)
        v = x[(((size_t)b * 512 + cibase + ci) * 50 + gr) * 50 + gc];
      xs[idx] = v;
    }
    for (int idx = t; idx < 144 * 64; idx += 256) {
      int row = idx >> 6, co = idx & 63;
      wl[idx] = Wsh[(size_t)(co0 + co) * 4608 + (size_t)cibase * 9 + row];
    }
    __syncthreads();
    for (int tap = 0; tap < 9; ++tap) {
      const int dt = ((tap / 3) - 1) * 52 + (tap % 3) - 1;
      #pragma unroll
      for (int ci = 0; ci < 16; ++ci) {
        const float4 bf = *(const float4*)(&wl[(ci * 9 + tap) * 64 + cog * 4]);
        double w0 = (double)bf.x, w1 = (double)bf.y, w2 = (double)bf.z, w3 = (double)bf.w;
        double a0 = (double)xs[ci * 260 + off[0] + dt];
        double a1 = (double)xs[ci * 260 + off[1] + dt];
        double a2 = (double)xs[ci * 260 + off[2] + dt];
        double a3 = (double)xs[ci * 260 + off[3] + dt];
        acc[0][0] += a0 * w0; acc[0][1] += a0 * w1; acc[0][2] += a0 * w2; acc[0][3] += a0 * w3;
        acc[1][0] += a1 * w0; acc[1][1] += a1 * w1; acc[1][2] += a1 * w2; acc[1][3] += a1 * w3;
        acc[2][0] += a2 * w0; acc[2][1] += a2 * w1; acc[2][2] += a2 * w2; acc[2][3] += a2 * w3;
        acc[3][0] += a3 * w0; acc[3][1] += a3 * w1; acc[3][2] += a3 * w2; acc[3][3] += a3 * w3;
      }
    }
    __syncthreads();
  }
  // numpy chain: f32 conv result, + f32 bias (f32 add), relu. We emulate with
  // exact conv (f64) rounded to f32, then f32 bias add. Stored as f64 carrier.
  #pragma unroll
  for (int i = 0; i < 4; ++i) {
    int co = co0 + cog * 4 + i;
    float bv = bsh[co];
    #pragma unroll
    for (int j = 0; j < 4; ++j) {
      if (pp[j] < 2500) {
        float v = (float)acc[j][i] + bv;       // f32 add, matching np
        v = fmaxf(v, 0.f);
        sh[((size_t)b * 512 + co) * 2500 + pp[j]] = (double)v;
      }
    }
  }
}

// ---------------- 1x1 heads (f64 accumulate) -> f32 logits -> np-replica f32 decode ----------------
__global__ __launch_bounds__(256) void k_heads(
    const double* __restrict__ sh, const float* __restrict__ Wc,
    const float* __restrict__ bc, const float* __restrict__ Wr,
    const float* __restrict__ br, float* __restrict__ out,
    float* __restrict__ scores, float* __restrict__ boxes)
{
#pragma clang fp contract(off)
  __shared__ double xs2[32][64];
  __shared__ float wcl[56][32];
  __shared__ float accs[64][56];   // f32 BIASED logits (np: f32 matmul + f32 bias)
  const int t = threadIdx.x;
  const int p0 = blockIdx.x * 64, b = blockIdx.y;
  const int px = t & 63, wg = t >> 6;
  double acc[14];
  #pragma unroll
  for (int j = 0; j < 14; ++j) acc[j] = 0.0;

  for (int cc = 0; cc < 16; ++cc) {
    for (int idx = t; idx < 2048; idx += 256) {
      int ci = idx >> 6, pl = idx & 63;
      int p = p0 + pl;
      xs2[ci][pl] = (p < 2500) ? sh[((size_t)b * 512 + cc * 32 + ci) * 2500 + p] : 0.0;
    }
    for (int idx = t; idx < 1792; idx += 256) {
      int co = idx >> 5, ci = idx & 31;
      float v = 0.f;
      if (co < 18) v = Wc[co * 512 + cc * 32 + ci];
      else if (co < 54) v = Wr[(co - 18) * 512 + cc * 32 + ci];
      wcl[co][ci] = v;
    }
    __syncthreads();
    for (int ci = 0; ci < 32; ++ci) {
      double a = xs2[ci][px];
      #pragma unroll
      for (int j = 0; j < 14; ++j) acc[j] += a * (double)wcl[wg * 14 + j][ci];
    }
    __syncthreads();
  }
  #pragma unroll
  for (int j = 0; j < 14; ++j) {
    int co = wg * 14 + j;
    float bias = (co < 18) ? bc[co] : ((co < 54) ? br[co - 18] : 0.f);
    accs[px][co] = (float)acc[j] + bias;    // round matmul to f32, f32 bias add
  }
  __syncthreads();

  // cls output: f32 softmax, correctly-rounded exp, f32 div
  for (int e = t; e < 64 * 18; e += 256) {
    int pxl = e / 18, c = e - pxl * 18;
    int p = p0 + pxl;
    if (p < 2500) {
      int a = c >> 1, k = c & 1;
      float l0 = accs[pxl][2 * a];
      float l1 = accs[pxl][2 * a + 1];
      float mm = fmaxf(l0, l1);
      float e0 = cr_expf(l0 - mm);
      float e1 = cr_expf(l1 - mm);
      float sum = e0 + e1;
      out[OUT_CLS + ((size_t)b * NANCH + (size_t)p * 9 + a) * 2 + k] = (k ? e1 : e0) / sum;
    }
  }
  // reg output (f32 biased logits)
  for (int e = t; e < 64 * 36; e += 256) {
    int pxl = e / 36, c = e - pxl * 36;
    int p = p0 + pxl;
    if (p < 2500)
      out[((size_t)b * NANCH + (size_t)p * 9 + (c >> 2)) * 4 + (c & 3)] = accs[pxl][18 + c];
  }
  // scores + decoded boxes: numpy-replica f32 — separate mul/add ufunc steps,
  // correctly-rounded f32 exp, clip = min(max(.,0),800).
  for (int e = t; e < 64 * 9; e += 256) {
    int pxl = e / 9, a = e - pxl * 9;
    int p = p0 + pxl;
    if (p < 2500) {
      float l0 = accs[pxl][2 * a];
      float l1 = accs[pxl][2 * a + 1];
      float mm = fmaxf(l0, l1);
      float e0 = cr_expf(l0 - mm);
      float e1 = cr_expf(l1 - mm);
      float fg = e1 / (e0 + e1);
      float dy = accs[pxl][18 + a * 4 + 0];
      float dx = accs[pxl][18 + a * 4 + 1];
      float dh = accs[pxl][18 + a * 4 + 2];
      float dw = accs[pxl][18 + a * 4 + 3];
      int yy = p / 50, xx = p - yy * 50;
      float ay1, ax1, ay2, ax2;
      anchor4(a, yy, xx, ay1, ax1, ay2, ax2);
      float ha  = ay2 - ay1;                 // np: f32 sub
      float wa2 = ax2 - ax1;
      float cya = ay1 + 0.5f * ha;           // np: mul then add (separate)
      float cxa = ax1 + 0.5f * wa2;
      float cy = dy * ha;  cy = cy + cya;    // separate mul, add
      float cx = dx * wa2; cx = cx + cxa;
      float hh = cr_expf(dh); hh = hh * ha;  // exp then mul
      float ww = cr_expf(dw); ww = ww * wa2;
      float t1;
      t1 = 0.5f * hh; float y1 = cy - t1; y1 = fminf(fmaxf(y1, 0.f), 800.f);
      t1 = 0.5f * ww; float x1 = cx - t1; x1 = fminf(fmaxf(x1, 0.f), 800.f);
      t1 = 0.5f * hh; float y2 = cy + t1; y2 = fminf(fmaxf(y2, 0.f), 800.f);
      t1 = 0.5f * ww; float x2 = cx + t1; x2 = fminf(fmaxf(x2, 0.f), 800.f);
      bool keep = (y2 - y1 >= 16.f) && (x2 - x1 >= 16.f);
      size_t gi = (size_t)b * NANCH + (size_t)p * 9 + a;
      scores[gi] = keep ? fg : -INFINITY;
      *(float4*)(boxes + gi * 4) = make_float4(y1, x1, y2, x2);
    }
  }
}

// ---------------- anchors output ----------------
__global__ __launch_bounds__(256) void k_anchors(float* __restrict__ out) {
  int i = blockIdx.x * 256 + threadIdx.x;
  if (i < NANCH) {
    int p = i / 9, a = i - p * 9;
    int yy = p / 50, xx = p - yy * 50;
    float y1, x1, y2, x2;
    anchor4(a, yy, xx, y1, x1, y2, x2);
    *(float4*)(out + OUT_ANCH + (size_t)i * 4) = make_float4(y1, x1, y2, x2);
  }
}

// ---------------- radix-select + stable compaction + NMS (f32, proven) ----------------
__global__ __launch_bounds__(1024) void k_nms(
    const float* __restrict__ scores, const float* __restrict__ boxes,
    float* __restrict__ out)
{
#pragma clang fp contract(off)
  const int b = blockIdx.x;
  const float* s = scores + (size_t)b * NANCH;
  const float* bx = boxes + (size_t)b * NANCH * 4;
  const int t = threadIdx.x;
  const int lane = t & 63, wid = t >> 6;
  __shared__ float cscore[6000];
  __shared__ float4 cbox[6000];
  __shared__ unsigned sHist[256];
  __shared__ unsigned sScan[17];
  __shared__ float wred_s[16];
  __shared__ int wred_e[16];
  __shared__ unsigned sPrefix, sKr, sG;
  __shared__ float sWinS;
  __shared__ int sWinE;

  for (int e = t; e < 6000; e += 1024) {
    cscore[e] = -INFINITY;
    cbox[e] = make_float4(0.f, 0.f, 0.f, 0.f);
  }
  if (t == 0) { sPrefix = 0u; sKr = 6000u; sG = 0u; }
  __syncthreads();

  for (int pass = 0; pass < 4; ++pass) {
    const int shift = 24 - 8 * pass;
    if (t < 256) sHist[t] = 0u;
    __syncthreads();
    const unsigned pref = sPrefix;
    const unsigned himask = (pass == 0) ? 0u : (0xFFFFFFFFu << (shift + 8));
    for (int i = t; i < NANCH; i += 1024) {
      unsigned key = keyOf(s[i]);
      if ((key & himask) == pref) atomicAdd(&sHist[(key >> shift) & 255u], 1u);
    }
    __syncthreads();
    if (t == 0) {
      unsigned Kr = sKr, acc = 0; int dsel = 0;
      for (int d = 255; d >= 0; --d) {
        unsigned c = sHist[d];
        if (acc + c >= Kr) { dsel = d; break; }
        acc += c;
      }
      sPrefix = pref | ((unsigned)dsel << shift);
      sKr = Kr - acc;
    }
    __syncthreads();
  }
  const unsigned cut = sPrefix;

  unsigned cg = 0;
  for (int i = t; i < NANCH; i += 1024)
    if (keyOf(s[i]) > cut) cg++;
  atomicAdd(&sG, cg);
  __syncthreads();
  const unsigned Gc = sG;
  const unsigned R = (Gc < 6000u) ? (6000u - Gc) : 0u;

  unsigned run_gt = 0, run_eq = 0;
  for (int chunk = 0; chunk < 22; ++chunk) {
    int i = (chunk << 10) + t;
    float sv = 0.f; unsigned key = 0u;
    if (i < NANCH) { sv = s[i]; key = keyOf(sv); }
    unsigned item = (i < NANCH) ? ((key > cut) ? 0x10000u : ((key == cut) ? 1u : 0u)) : 0u;
    unsigned inc = item;
    #pragma unroll
    for (int d = 1; d < 64; d <<= 1) {
      unsigned n = __shfl_up(inc, d, 64);
      if (lane >= d) inc += n;
    }
    if (lane == 63) sScan[wid] = inc;
    __syncthreads();
    if (t == 0) {
      unsigned a2 = 0;
      for (int k = 0; k < 16; ++k) { unsigned tmp = sScan[k]; sScan[k] = a2; a2 += tmp; }
      sScan[16] = a2;
    }
    __syncthreads();
    unsigned excl = inc - item + sScan[wid];
    unsigned total = sScan[16];
    __syncthreads();
    unsigned gt_b = run_gt + (excl >> 16);
    unsigned eq_b = run_eq + (excl & 0xFFFFu);
    bool sel = ((item >> 16) != 0u) || (((item & 0xFFFFu) != 0u) && (eq_b < R));
    if (sel) {
      unsigned pos = gt_b + (eq_b < R ? eq_b : R);
      if (pos < 6000u) {
        cscore[pos] = sv;
        cbox[pos] = *(const float4*)(bx + (size_t)i * 4);
      }
    }
    run_gt += (total >> 16); run_eq += (total & 0xFFFFu);
  }
  __syncthreads();

  float sreg[6]; float4 breg[6];
  #pragma unroll
  for (int j = 0; j < 6; ++j) {
    int e = t + (j << 10);
    if (e < 6000) {
      sreg[j] = cscore[e];
      breg[j] = cbox[e];
    } else {
      sreg[j] = -INFINITY;
      breg[j] = make_float4(0.f, 0.f, 0.f, 0.f);
    }
  }
  __syncthreads();

  for (int it = 0; it < 300; ++it) {
    float bs = sreg[0]; int be = t;
    #pragma unroll
    for (int j = 1; j < 6; ++j) {
      if (sreg[j] > bs) { bs = sreg[j]; be = t + (j << 10); }
    }
    #pragma unroll
    for (int d = 1; d < 64; d <<= 1) {
      float os = __shfl_xor(bs, d);
      int oe = __shfl_xor(be, d);
      if (os > bs || (os == bs && oe < be)) { bs = os; be = oe; }
    }
    if (lane == 0) { wred_s[wid] = bs; wred_e[wid] = be; }
    __syncthreads();
    if (t == 0) {
      float ws0 = wred_s[0]; int we0 = wred_e[0];
      for (int k = 1; k < 16; ++k) {
        float s2 = wred_s[k]; int e2 = wred_e[k];
        if (s2 > ws0 || (s2 == ws0 && e2 < we0)) { ws0 = s2; we0 = e2; }
      }
      sWinS = ws0; sWinE = we0;
    }
    __syncthreads();
    const float wsc = sWinS; const int we = sWinE;
    const float4 wb = cbox[we];
    const bool valid = (wsc > -INFINITY);
    if (t == 0) {
      const float m = valid ? 1.f : 0.f;
      size_t ro = OUT_ROIS + ((size_t)b * 300 + it) * 4;
      out[ro + 0] = wb.x * m; out[ro + 1] = wb.y * m;
      out[ro + 2] = wb.z * m; out[ro + 3] = wb.w * m;
      out[OUT_ROIID + (size_t)b * 300 + it] = valid ? (float)b : 0.f;
    }
    {
      const float a1 = (wb.z - wb.x) * (wb.w - wb.y);
      #pragma unroll
      for (int j = 0; j < 6; ++j) {
        float ty1 = fmaxf(wb.x, breg[j].x);
        float tx1 = fmaxf(wb.y, breg[j].y);
        float ty2 = fminf(wb.z, breg[j].z);
        float tx2 = fminf(wb.w, breg[j].w);
        float inter = fmaxf(ty2 - ty1, 0.f) * fmaxf(tx2 - tx1, 0.f);
        float a2 = (breg[j].z - breg[j].x) * (breg[j].w - breg[j].y);
        float ov = inter / (a1 + a2 - inter + 1e-9f);
        if (ov > 0.7f) sreg[j] = -INFINITY;
      }
    }
    __syncthreads();
  }
}

extern "C" void kernel_launch(void* const* d_in, const int* in_sizes, int n_in,
                              void* d_out, int out_size, void* d_ws, size_t ws_size,
                              hipStream_t stream) {
  (void)in_sizes; (void)n_in; (void)out_size;
  // ws: sh 10.24M f64 (81.92MB) | scores 180K f32 | boxes 720K f32
  const size_t need = (size_t)10240000 * 8 + (size_t)(180000 + 720000) * 4;
  if (ws_size < need) return;
  const float* x   = (const float*)d_in[0];
  const float* Wsh = (const float*)d_in[1];
  const float* bsh = (const float*)d_in[2];
  const float* Wc  = (const float*)d_in[3];
  const float* bc  = (const float*)d_in[4];
  const float* Wr  = (const float*)d_in[5];
  const float* br  = (const float*)d_in[6];
  float* out = (float*)d_out;
  double* sh = (double*)d_ws;
  float* scores = (float*)(sh + 10240000);
  float* boxes  = scores + 180000;

  hipLaunchKernelGGL(k_conv3x3, dim3(40, 8, 8), dim3(256), 0, stream, x, Wsh, bsh, sh);
  hipLaunchKernelGGL(k_heads,   dim3(40, 8),    dim3(256), 0, stream, sh, Wc, bc, Wr, br, out, scores, boxes);
  hipLaunchKernelGGL(k_anchors, dim3(88),       dim3(256), 0, stream, out);
  hipLaunchKernelGGL(k_nms,     dim3(8),        dim3(1024), 0, stream, scores, boxes, out);
}

// Round 13
// 4493.075 us; speedup vs baseline: 1.3663x; 1.3663x over previous
//
#include <hip/hip_runtime.h>
#include <cmath>

#define NANCH 22500

// out layout offsets (floats)
#define OUT_REG   0
#define OUT_CLS   720000
#define OUT_ROIS  1080000
#define OUT_ROIID 1089600
#define OUT_ANCH  1092000

__device__ __forceinline__ unsigned keyOf(float f) {
  unsigned u = __float_as_uint(f);
  return (u & 0x80000000u) ? ~u : (u | 0x80000000u);
}

// correctly-rounded f32 exp: f64 exp then round once (glibc expf-equivalent)
__device__ __forceinline__ float cr_expf(float x) {
  return (float)exp((double)x);
}

// anchors: bit-match np _anchor_base (f64 math, f32 cast) + f32 shift add
__device__ __forceinline__ void anchor4(int a, int yy, int xx,
    float& y1, float& x1, float& y2, float& x2) {
  int ri = a / 3, si = a - ri * 3;
  double r = (ri == 0) ? 0.5 : ((ri == 1) ? 1.0 : 2.0);
  double s = (si == 0) ? 8.0 : ((si == 1) ? 16.0 : 32.0);
  double h = 16.0 * s * sqrt(r);
  double w = 16.0 * s * sqrt(1.0 / r);
  float sy = (float)(yy * 16), sx = (float)(xx * 16);
  y1 = sy + (float)(8.0 - 0.5 * h);
  x1 = sx + (float)(8.0 - 0.5 * w);
  y2 = sy + (float)(8.0 + 0.5 * h);
  x2 = sx + (float)(8.0 + 0.5 * w);
}

// ---------------- conv3x3 512->512 + bias + relu (f64 fma, f64 LDS) ----------------
// K-order preserved from the passing round: cc(0..31) outer, tap(0..8), ci(0..15).
// Change vs r12: fma() instead of mul+add (f64 delta ~4e-15 rel — below pick-flip
// granularity), f64-converted LDS operands (no inner cvt), conflict-free px map.
__global__ __launch_bounds__(256) void k_conv3x3(
    const float* __restrict__ x, const float* __restrict__ Wsh,
    const float* __restrict__ bsh, double* __restrict__ sh)
{
  __shared__ double xs[16 * 260];   // [ci16][row5][col52] f64, 33.3KB
  __shared__ double wl[16 * 64];    // [ci16][co64] f64 for current tap, 8KB
  const int t = threadIdx.x;
  const int p0 = blockIdx.x * 64, co0 = blockIdx.y * 64, b = blockIdx.z;
  const int pxg = t & 15, cog = t >> 4;
  const int r0 = p0 / 50;
  int off[4], pp[4];
  #pragma unroll
  for (int j = 0; j < 4; ++j) {
    int p = p0 + pxg + 16 * j;      // lane-contiguous px -> conflict-free ds_read_b64
    pp[j] = p;
    int q = (p < 2500) ? p : 2499;
    int r = q / 50, c = q - r * 50;
    off[j] = (r - r0 + 1) * 52 + c + 1;
  }
  double acc[4][4];
  #pragma unroll
  for (int j = 0; j < 4; ++j)
    #pragma unroll
    for (int i = 0; i < 4; ++i) acc[j][i] = 0.0;

  for (int cc = 0; cc < 32; ++cc) {
    const int cibase = cc * 16;
    // stage x patch as f64: rows r0-1..r0+3, cols -1..50 (zero padded)
    for (int idx = t; idx < 16 * 260; idx += 256) {
      int ci = idx / 260;
      int rem = idx - ci * 260;
      int rr = rem / 52, cs = rem - rr * 52;
      int gr = r0 - 1 + rr, gc = cs - 1;
      float v = 0.f;
      if (gr >= 0 && gr < 50 && gc >= 0 && gc < 50)
        v = x[(((size_t)b * 512 + cibase + ci) * 50 + gr) * 50 + gc];
      xs[idx] = (double)v;
    }
    for (int tap = 0; tap < 9; ++tap) {
      // stage this tap's weights as f64 (order-preserving per-tap tiles)
      for (int idx = t; idx < 1024; idx += 256) {
        int ci = idx >> 6, co = idx & 63;
        wl[idx] = (double)Wsh[(size_t)(co0 + co) * 4608 + (size_t)(cibase + ci) * 9 + tap];
      }
      __syncthreads();
      const int dt = ((tap / 3) - 1) * 52 + (tap % 3) - 1;
      #pragma unroll
      for (int ci = 0; ci < 16; ++ci) {
        const double w0 = wl[ci * 64 + cog * 4 + 0];
        const double w1 = wl[ci * 64 + cog * 4 + 1];
        const double w2 = wl[ci * 64 + cog * 4 + 2];
        const double w3 = wl[ci * 64 + cog * 4 + 3];
        const double a0 = xs[ci * 260 + off[0] + dt];
        const double a1 = xs[ci * 260 + off[1] + dt];
        const double a2 = xs[ci * 260 + off[2] + dt];
        const double a3 = xs[ci * 260 + off[3] + dt];
        acc[0][0] = fma(a0, w0, acc[0][0]); acc[0][1] = fma(a0, w1, acc[0][1]);
        acc[0][2] = fma(a0, w2, acc[0][2]); acc[0][3] = fma(a0, w3, acc[0][3]);
        acc[1][0] = fma(a1, w0, acc[1][0]); acc[1][1] = fma(a1, w1, acc[1][1]);
        acc[1][2] = fma(a1, w2, acc[1][2]); acc[1][3] = fma(a1, w3, acc[1][3]);
        acc[2][0] = fma(a2, w0, acc[2][0]); acc[2][1] = fma(a2, w1, acc[2][1]);
        acc[2][2] = fma(a2, w2, acc[2][2]); acc[2][3] = fma(a2, w3, acc[2][3]);
        acc[3][0] = fma(a3, w0, acc[3][0]); acc[3][1] = fma(a3, w1, acc[3][1]);
        acc[3][2] = fma(a3, w2, acc[3][2]); acc[3][3] = fma(a3, w3, acc[3][3]);
      }
      __syncthreads();
    }
  }
  // numpy interface: exact f64 conv -> f32 round -> f32 bias add -> relu
  #pragma unroll
  for (int i = 0; i < 4; ++i) {
    int co = co0 + cog * 4 + i;
    float bv = bsh[co];
    #pragma unroll
    for (int j = 0; j < 4; ++j) {
      if (pp[j] < 2500) {
        float v = (float)acc[j][i] + bv;
        v = fmaxf(v, 0.f);
        sh[((size_t)b * 512 + co) * 2500 + pp[j]] = (double)v;
      }
    }
  }
}

// ---------------- 1x1 heads (f64 accumulate) -> f32 logits -> np-replica f32 decode ----------------
__global__ __launch_bounds__(256) void k_heads(
    const double* __restrict__ sh, const float* __restrict__ Wc,
    const float* __restrict__ bc, const float* __restrict__ Wr,
    const float* __restrict__ br, float* __restrict__ out,
    float* __restrict__ scores, float* __restrict__ boxes)
{
#pragma clang fp contract(off)
  __shared__ double xs2[32][64];
  __shared__ float wcl[56][32];
  __shared__ float accs[64][56];   // f32 BIASED logits
  const int t = threadIdx.x;
  const int p0 = blockIdx.x * 64, b = blockIdx.y;
  const int px = t & 63, wg = t >> 6;
  double acc[14];
  #pragma unroll
  for (int j = 0; j < 14; ++j) acc[j] = 0.0;

  for (int cc = 0; cc < 16; ++cc) {
    for (int idx = t; idx < 2048; idx += 256) {
      int ci = idx >> 6, pl = idx & 63;
      int p = p0 + pl;
      xs2[ci][pl] = (p < 2500) ? sh[((size_t)b * 512 + cc * 32 + ci) * 2500 + p] : 0.0;
    }
    for (int idx = t; idx < 1792; idx += 256) {
      int co = idx >> 5, ci = idx & 31;
      float v = 0.f;
      if (co < 18) v = Wc[co * 512 + cc * 32 + ci];
      else if (co < 54) v = Wr[(co - 18) * 512 + cc * 32 + ci];
      wcl[co][ci] = v;
    }
    __syncthreads();
    for (int ci = 0; ci < 32; ++ci) {
      double a = xs2[ci][px];
      #pragma unroll
      for (int j = 0; j < 14; ++j) acc[j] += a * (double)wcl[wg * 14 + j][ci];
    }
    __syncthreads();
  }
  #pragma unroll
  for (int j = 0; j < 14; ++j) {
    int co = wg * 14 + j;
    float bias = (co < 18) ? bc[co] : ((co < 54) ? br[co - 18] : 0.f);
    accs[px][co] = (float)acc[j] + bias;    // round matmul to f32, f32 bias add
  }
  __syncthreads();

  // cls output: f32 softmax, correctly-rounded exp, f32 div
  for (int e = t; e < 64 * 18; e += 256) {
    int pxl = e / 18, c = e - pxl * 18;
    int p = p0 + pxl;
    if (p < 2500) {
      int a = c >> 1, k = c & 1;
      float l0 = accs[pxl][2 * a];
      float l1 = accs[pxl][2 * a + 1];
      float mm = fmaxf(l0, l1);
      float e0 = cr_expf(l0 - mm);
      float e1 = cr_expf(l1 - mm);
      float sum = e0 + e1;
      out[OUT_CLS + ((size_t)b * NANCH + (size_t)p * 9 + a) * 2 + k] = (k ? e1 : e0) / sum;
    }
  }
  // reg output (f32 biased logits)
  for (int e = t; e < 64 * 36; e += 256) {
    int pxl = e / 36, c = e - pxl * 36;
    int p = p0 + pxl;
    if (p < 2500)
      out[((size_t)b * NANCH + (size_t)p * 9 + (c >> 2)) * 4 + (c & 3)] = accs[pxl][18 + c];
  }
  // scores + decoded boxes: numpy-replica f32
  for (int e = t; e < 64 * 9; e += 256) {
    int pxl = e / 9, a = e - pxl * 9;
    int p = p0 + pxl;
    if (p < 2500) {
      float l0 = accs[pxl][2 * a];
      float l1 = accs[pxl][2 * a + 1];
      float mm = fmaxf(l0, l1);
      float e0 = cr_expf(l0 - mm);
      float e1 = cr_expf(l1 - mm);
      float fg = e1 / (e0 + e1);
      float dy = accs[pxl][18 + a * 4 + 0];
      float dx = accs[pxl][18 + a * 4 + 1];
      float dh = accs[pxl][18 + a * 4 + 2];
      float dw = accs[pxl][18 + a * 4 + 3];
      int yy = p / 50, xx = p - yy * 50;
      float ay1, ax1, ay2, ax2;
      anchor4(a, yy, xx, ay1, ax1, ay2, ax2);
      float ha  = ay2 - ay1;
      float wa2 = ax2 - ax1;
      float cya = ay1 + 0.5f * ha;
      float cxa = ax1 + 0.5f * wa2;
      float cy = dy * ha;  cy = cy + cya;
      float cx = dx * wa2; cx = cx + cxa;
      float hh = cr_expf(dh); hh = hh * ha;
      float ww = cr_expf(dw); ww = ww * wa2;
      float t1;
      t1 = 0.5f * hh; float y1 = cy - t1; y1 = fminf(fmaxf(y1, 0.f), 800.f);
      t1 = 0.5f * ww; float x1 = cx - t1; x1 = fminf(fmaxf(x1, 0.f), 800.f);
      t1 = 0.5f * hh; float y2 = cy + t1; y2 = fminf(fmaxf(y2, 0.f), 800.f);
      t1 = 0.5f * ww; float x2 = cx + t1; x2 = fminf(fmaxf(x2, 0.f), 800.f);
      bool keep = (y2 - y1 >= 16.f) && (x2 - x1 >= 16.f);
      size_t gi = (size_t)b * NANCH + (size_t)p * 9 + a;
      scores[gi] = keep ? fg : -INFINITY;
      *(float4*)(boxes + gi * 4) = make_float4(y1, x1, y2, x2);
    }
  }
}

// ---------------- anchors output ----------------
__global__ __launch_bounds__(256) void k_anchors(float* __restrict__ out) {
  int i = blockIdx.x * 256 + threadIdx.x;
  if (i < NANCH) {
    int p = i / 9, a = i - p * 9;
    int yy = p / 50, xx = p - yy * 50;
    float y1, x1, y2, x2;
    anchor4(a, yy, xx, y1, x1, y2, x2);
    *(float4*)(out + OUT_ANCH + (size_t)i * 4) = make_float4(y1, x1, y2, x2);
  }
}

// ---------------- radix-select + stable compaction + NMS (f32, proven) ----------------
__global__ __launch_bounds__(1024) void k_nms(
    const float* __restrict__ scores, const float* __restrict__ boxes,
    float* __restrict__ out)
{
#pragma clang fp contract(off)
  const int b = blockIdx.x;
  const float* s = scores + (size_t)b * NANCH;
  const float* bx = boxes + (size_t)b * NANCH * 4;
  const int t = threadIdx.x;
  const int lane = t & 63, wid = t >> 6;
  __shared__ float cscore[6000];
  __shared__ float4 cbox[6000];
  __shared__ unsigned sHist[256];
  __shared__ unsigned sScan[17];
  __shared__ float wred_s[16];
  __shared__ int wred_e[16];
  __shared__ unsigned sPrefix, sKr, sG;
  __shared__ float sWinS;
  __shared__ int sWinE;

  for (int e = t; e < 6000; e += 1024) {
    cscore[e] = -INFINITY;
    cbox[e] = make_float4(0.f, 0.f, 0.f, 0.f);
  }
  if (t == 0) { sPrefix = 0u; sKr = 6000u; sG = 0u; }
  __syncthreads();

  for (int pass = 0; pass < 4; ++pass) {
    const int shift = 24 - 8 * pass;
    if (t < 256) sHist[t] = 0u;
    __syncthreads();
    const unsigned pref = sPrefix;
    const unsigned himask = (pass == 0) ? 0u : (0xFFFFFFFFu << (shift + 8));
    for (int i = t; i < NANCH; i += 1024) {
      unsigned key = keyOf(s[i]);
      if ((key & himask) == pref) atomicAdd(&sHist[(key >> shift) & 255u], 1u);
    }
    __syncthreads();
    if (t == 0) {
      unsigned Kr = sKr, acc = 0; int dsel = 0;
      for (int d = 255; d >= 0; --d) {
        unsigned c = sHist[d];
        if (acc + c >= Kr) { dsel = d; break; }
        acc += c;
      }
      sPrefix = pref | ((unsigned)dsel << shift);
      sKr = Kr - acc;
    }
    __syncthreads();
  }
  const unsigned cut = sPrefix;

  unsigned cg = 0;
  for (int i = t; i < NANCH; i += 1024)
    if (keyOf(s[i]) > cut) cg++;
  atomicAdd(&sG, cg);
  __syncthreads();
  const unsigned Gc = sG;
  const unsigned R = (Gc < 6000u) ? (6000u - Gc) : 0u;

  unsigned run_gt = 0, run_eq = 0;
  for (int chunk = 0; chunk < 22; ++chunk) {
    int i = (chunk << 10) + t;
    float sv = 0.f; unsigned key = 0u;
    if (i < NANCH) { sv = s[i]; key = keyOf(sv); }
    unsigned item = (i < NANCH) ? ((key > cut) ? 0x10000u : ((key == cut) ? 1u : 0u)) : 0u;
    unsigned inc = item;
    #pragma unroll
    for (int d = 1; d < 64; d <<= 1) {
      unsigned n = __shfl_up(inc, d, 64);
      if (lane >= d) inc += n;
    }
    if (lane == 63) sScan[wid] = inc;
    __syncthreads();
    if (t == 0) {
      unsigned a2 = 0;
      for (int k = 0; k < 16; ++k) { unsigned tmp = sScan[k]; sScan[k] = a2; a2 += tmp; }
      sScan[16] = a2;
    }
    __syncthreads();
    unsigned excl = inc - item + sScan[wid];
    unsigned total = sScan[16];
    __syncthreads();
    unsigned gt_b = run_gt + (excl >> 16);
    unsigned eq_b = run_eq + (excl & 0xFFFFu);
    bool sel = ((item >> 16) != 0u) || (((item & 0xFFFFu) != 0u) && (eq_b < R));
    if (sel) {
      unsigned pos = gt_b + (eq_b < R ? eq_b : R);
      if (pos < 6000u) {
        cscore[pos] = sv;
        cbox[pos] = *(const float4*)(bx + (size_t)i * 4);
      }
    }
    run_gt += (total >> 16); run_eq += (total & 0xFFFFu);
  }
  __syncthreads();

  float sreg[6]; float4 breg[6];
  #pragma unroll
  for (int j = 0; j < 6; ++j) {
    int e = t + (j << 10);
    if (e < 6000) {
      sreg[j] = cscore[e];
      breg[j] = cbox[e];
    } else {
      sreg[j] = -INFINITY;
      breg[j] = make_float4(0.f, 0.f, 0.f, 0.f);
    }
  }
  __syncthreads();

  for (int it = 0; it < 300; ++it) {
    float bs = sreg[0]; int be = t;
    #pragma unroll
    for (int j = 1; j < 6; ++j) {
      if (sreg[j] > bs) { bs = sreg[j]; be = t + (j << 10); }
    }
    #pragma unroll
    for (int d = 1; d < 64; d <<= 1) {
      float os = __shfl_xor(bs, d);
      int oe = __shfl_xor(be, d);
      if (os > bs || (os == bs && oe < be)) { bs = os; be = oe; }
    }
    if (lane == 0) { wred_s[wid] = bs; wred_e[wid] = be; }
    __syncthreads();
    if (t == 0) {
      float ws0 = wred_s[0]; int we0 = wred_e[0];
      for (int k = 1; k < 16; ++k) {
        float s2 = wred_s[k]; int e2 = wred_e[k];
        if (s2 > ws0 || (s2 == ws0 && e2 < we0)) { ws0 = s2; we0 = e2; }
      }
      sWinS = ws0; sWinE = we0;
    }
    __syncthreads();
    const float wsc = sWinS; const int we = sWinE;
    const float4 wb = cbox[we];
    const bool valid = (wsc > -INFINITY);
    if (t == 0) {
      const float m = valid ? 1.f : 0.f;
      size_t ro = OUT_ROIS + ((size_t)b * 300 + it) * 4;
      out[ro + 0] = wb.x * m; out[ro + 1] = wb.y * m;
      out[ro + 2] = wb.z * m; out[ro + 3] = wb.w * m;
      out[OUT_ROIID + (size_t)b * 300 + it] = valid ? (float)b : 0.f;
    }
    {
      const float a1 = (wb.z - wb.x) * (wb.w - wb.y);
      #pragma unroll
      for (int j = 0; j < 6; ++j) {
        float ty1 = fmaxf(wb.x, breg[j].x);
        float tx1 = fmaxf(wb.y, breg[j].y);
        float ty2 = fminf(wb.z, breg[j].z);
        float tx2 = fminf(wb.w, breg[j].w);
        float inter = fmaxf(ty2 - ty1, 0.f) * fmaxf(tx2 - tx1, 0.f);
        float a2 = (breg[j].z - breg[j].x) * (breg[j].w - breg[j].y);
        float ov = inter / (a1 + a2 - inter + 1e-9f);
        if (ov > 0.7f) sreg[j] = -INFINITY;
      }
    }
    __syncthreads();
  }
}

extern "C" void kernel_launch(void* const* d_in, const int* in_sizes, int n_in,
                              void* d_out, int out_size, void* d_ws, size_t ws_size,
                              hipStream_t stream) {
  (void)in_sizes; (void)n_in; (void)out_size;
  // ws: sh 10.24M f64 (81.92MB) | scores 180K f32 | boxes 720K f32
  const size_t need = (size_t)10240000 * 8 + (size_t)(180000 + 720000) * 4;
  if (ws_size < need) return;
  const float* x   = (const float*)d_in[0];
  const float* Wsh = (const float*)d_in[1];
  const float* bsh = (const float*)d_in[2];
  const float* Wc  = (const float*)d_in[3];
  const float* bc  = (const float*)d_in[4];
  const float* Wr  = (const float*)d_in[5];
  const float* br  = (const float*)d_in[6];
  float* out = (float*)d_out;
  double* sh = (double*)d_ws;
  float* scores = (float*)(sh + 10240000);
  float* boxes  = scores + 180000;

  hipLaunchKernelGGL(k_conv3x3, dim3(40, 8, 8), dim3(256), 0, stream, x, Wsh, bsh, sh);
  hipLaunchKernelGGL(k_heads,   dim3(40, 8),    dim3(256), 0, stream, sh, Wc, bc, Wr, br, out, scores, boxes);
  hipLaunchKernelGGL(k_anchors, dim3(88),       dim3(256), 0, stream, out);
  hipLaunchKernelGGL(k_nms,     dim3(8),        dim3(1024), 0, stream, scores, boxes, out);
}

// Round 14
// 3847.343 us; speedup vs baseline: 1.5957x; 1.1678x over previous
//
#include <hip/hip_runtime.h>
#include <cmath>

#define NANCH 22500

// out layout offsets (floats)
#define OUT_REG   0
#define OUT_CLS   720000
#define OUT_ROIS  1080000
#define OUT_ROIID 1089600
#define OUT_ANCH  1092000

__device__ __forceinline__ unsigned keyOf(float f) {
  unsigned u = __float_as_uint(f);
  return (u & 0x80000000u) ? ~u : (u | 0x80000000u);
}

// correctly-rounded f32 exp: f64 exp then round once (glibc expf-equivalent)
__device__ __forceinline__ float cr_expf(float x) {
  return (float)exp((double)x);
}

// anchors: bit-match np _anchor_base (f64 math, f32 cast) + f32 shift add
__device__ __forceinline__ void anchor4(int a, int yy, int xx,
    float& y1, float& x1, float& y2, float& x2) {
  int ri = a / 3, si = a - ri * 3;
  double r = (ri == 0) ? 0.5 : ((ri == 1) ? 1.0 : 2.0);
  double s = (si == 0) ? 8.0 : ((si == 1) ? 16.0 : 32.0);
  double h = 16.0 * s * sqrt(r);
  double w = 16.0 * s * sqrt(1.0 / r);
  float sy = (float)(yy * 16), sx = (float)(xx * 16);
  y1 = sy + (float)(8.0 - 0.5 * h);
  x1 = sx + (float)(8.0 - 0.5 * w);
  y2 = sy + (float)(8.0 + 0.5 * h);
  x2 = sx + (float)(8.0 + 0.5 * w);
}

// ---------------- conv3x3 512->512 + bias + relu (f64 fma; f32 acts in LDS) ----------------
// Bit-exact vs r13: per-output accumulation order (cc -> tap -> ci) unchanged;
// activations are exact f32 (cvt to f64 in-register is exact). Thread tile
// 8px x 4co halves weight bytes/FMA; f32 acts halve activation bytes/FMA.
__global__ __launch_bounds__(256, 3) void k_conv3x3(
    const float* __restrict__ x, const float* __restrict__ Wsh,
    const float* __restrict__ bsh, double* __restrict__ sh)
{
  __shared__ float  xs[16 * 312];   // [ci16][6 rows][52 cols] f32, 20KB
  __shared__ double wl[16 * 64];    // [ci16][co64] f64 for current tap, 8KB
  const int t = threadIdx.x;
  const int px0 = blockIdx.x * 128, co0 = blockIdx.y * 64, b = blockIdx.z;
  const int pxg = t & 15, cog = t >> 4;
  const int r0 = px0 / 50;
  int off[8], pp[8];
  #pragma unroll
  for (int j = 0; j < 8; ++j) {
    int p = px0 + pxg + 16 * j;     // lane-contiguous px -> conflict-free b32 reads
    pp[j] = p;
    int q = (p < 2500) ? p : 2499;
    int r = q / 50, c = q - r * 50;
    off[j] = (r - r0 + 1) * 52 + c + 1;
  }
  double acc[8][4];
  #pragma unroll
  for (int j = 0; j < 8; ++j)
    #pragma unroll
    for (int i = 0; i < 4; ++i) acc[j][i] = 0.0;

  for (int cc = 0; cc < 32; ++cc) {
    const int cibase = cc * 16;
    // stage x patch as f32: rows r0-1..r0+4 (6 rows), cols -1..50, zero-padded
    for (int idx = t; idx < 16 * 312; idx += 256) {
      int ci = idx / 312;
      int rem = idx - ci * 312;
      int rr = rem / 52, cs = rem - rr * 52;
      int gr = r0 - 1 + rr, gc = cs - 1;
      float v = 0.f;
      if (gr >= 0 && gr < 50 && gc >= 0 && gc < 50)
        v = x[(((size_t)b * 512 + cibase + ci) * 50 + gr) * 50 + gc];
      xs[idx] = v;
    }
    for (int tap = 0; tap < 9; ++tap) {
      // stage this tap's weights as f64 (exact cvt at staging)
      for (int idx = t; idx < 1024; idx += 256) {
        int ci = idx >> 6, co = idx & 63;
        wl[idx] = (double)Wsh[(size_t)(co0 + co) * 4608 + (size_t)(cibase + ci) * 9 + tap];
      }
      __syncthreads();
      const int dt = ((tap / 3) - 1) * 52 + (tap % 3) - 1;
      #pragma unroll
      for (int ci = 0; ci < 16; ++ci) {
        const double w0 = wl[ci * 64 + cog * 4 + 0];
        const double w1 = wl[ci * 64 + cog * 4 + 1];
        const double w2 = wl[ci * 64 + cog * 4 + 2];
        const double w3 = wl[ci * 64 + cog * 4 + 3];
        double a[8];
        #pragma unroll
        for (int j = 0; j < 8; ++j)
          a[j] = (double)xs[ci * 312 + off[j] + dt];   // exact f32->f64
        #pragma unroll
        for (int j = 0; j < 8; ++j) {
          acc[j][0] = fma(a[j], w0, acc[j][0]);
          acc[j][1] = fma(a[j], w1, acc[j][1]);
          acc[j][2] = fma(a[j], w2, acc[j][2]);
          acc[j][3] = fma(a[j], w3, acc[j][3]);
        }
      }
      __syncthreads();
    }
  }
  // numpy interface: exact f64 conv -> f32 round -> f32 bias add -> relu
  #pragma unroll
  for (int i = 0; i < 4; ++i) {
    int co = co0 + cog * 4 + i;
    float bv = bsh[co];
    #pragma unroll
    for (int j = 0; j < 8; ++j) {
      if (pp[j] < 2500) {
        float v = (float)acc[j][i] + bv;
        v = fmaxf(v, 0.f);
        sh[((size_t)b * 512 + co) * 2500 + pp[j]] = (double)v;
      }
    }
  }
}

// ---------------- 1x1 heads (f64 accumulate) -> f32 logits -> np-replica f32 decode ----------------
__global__ __launch_bounds__(256) void k_heads(
    const double* __restrict__ sh, const float* __restrict__ Wc,
    const float* __restrict__ bc, const float* __restrict__ Wr,
    const float* __restrict__ br, float* __restrict__ out,
    float* __restrict__ scores, float* __restrict__ boxes)
{
#pragma clang fp contract(off)
  __shared__ double xs2[32][64];
  __shared__ float wcl[56][32];
  __shared__ float accs[64][56];   // f32 BIASED logits
  const int t = threadIdx.x;
  const int p0 = blockIdx.x * 64, b = blockIdx.y;
  const int px = t & 63, wg = t >> 6;
  double acc[14];
  #pragma unroll
  for (int j = 0; j < 14; ++j) acc[j] = 0.0;

  for (int cc = 0; cc < 16; ++cc) {
    for (int idx = t; idx < 2048; idx += 256) {
      int ci = idx >> 6, pl = idx & 63;
      int p = p0 + pl;
      xs2[ci][pl] = (p < 2500) ? sh[((size_t)b * 512 + cc * 32 + ci) * 2500 + p] : 0.0;
    }
    for (int idx = t; idx < 1792; idx += 256) {
      int co = idx >> 5, ci = idx & 31;
      float v = 0.f;
      if (co < 18) v = Wc[co * 512 + cc * 32 + ci];
      else if (co < 54) v = Wr[(co - 18) * 512 + cc * 32 + ci];
      wcl[co][ci] = v;
    }
    __syncthreads();
    for (int ci = 0; ci < 32; ++ci) {
      double a = xs2[ci][px];
      #pragma unroll
      for (int j = 0; j < 14; ++j) acc[j] += a * (double)wcl[wg * 14 + j][ci];
    }
    __syncthreads();
  }
  #pragma unroll
  for (int j = 0; j < 14; ++j) {
    int co = wg * 14 + j;
    float bias = (co < 18) ? bc[co] : ((co < 54) ? br[co - 18] : 0.f);
    accs[px][co] = (float)acc[j] + bias;    // round matmul to f32, f32 bias add
  }
  __syncthreads();

  // cls output: f32 softmax, correctly-rounded exp, f32 div
  for (int e = t; e < 64 * 18; e += 256) {
    int pxl = e / 18, c = e - pxl * 18;
    int p = p0 + pxl;
    if (p < 2500) {
      int a = c >> 1, k = c & 1;
      float l0 = accs[pxl][2 * a];
      float l1 = accs[pxl][2 * a + 1];
      float mm = fmaxf(l0, l1);
      float e0 = cr_expf(l0 - mm);
      float e1 = cr_expf(l1 - mm);
      float sum = e0 + e1;
      out[OUT_CLS + ((size_t)b * NANCH + (size_t)p * 9 + a) * 2 + k] = (k ? e1 : e0) / sum;
    }
  }
  // reg output (f32 biased logits)
  for (int e = t; e < 64 * 36; e += 256) {
    int pxl = e / 36, c = e - pxl * 36;
    int p = p0 + pxl;
    if (p < 2500)
      out[((size_t)b * NANCH + (size_t)p * 9 + (c >> 2)) * 4 + (c & 3)] = accs[pxl][18 + c];
  }
  // scores + decoded boxes: numpy-replica f32
  for (int e = t; e < 64 * 9; e += 256) {
    int pxl = e / 9, a = e - pxl * 9;
    int p = p0 + pxl;
    if (p < 2500) {
      float l0 = accs[pxl][2 * a];
      float l1 = accs[pxl][2 * a + 1];
      float mm = fmaxf(l0, l1);
      float e0 = cr_expf(l0 - mm);
      float e1 = cr_expf(l1 - mm);
      float fg = e1 / (e0 + e1);
      float dy = accs[pxl][18 + a * 4 + 0];
      float dx = accs[pxl][18 + a * 4 + 1];
      float dh = accs[pxl][18 + a * 4 + 2];
      float dw = accs[pxl][18 + a * 4 + 3];
      int yy = p / 50, xx = p - yy * 50;
      float ay1, ax1, ay2, ax2;
      anchor4(a, yy, xx, ay1, ax1, ay2, ax2);
      float ha  = ay2 - ay1;
      float wa2 = ax2 - ax1;
      float cya = ay1 + 0.5f * ha;
      float cxa = ax1 + 0.5f * wa2;
      float cy = dy * ha;  cy = cy + cya;
      float cx = dx * wa2; cx = cx + cxa;
      float hh = cr_expf(dh); hh = hh * ha;
      float ww = cr_expf(dw); ww = ww * wa2;
      float t1;
      t1 = 0.5f * hh; float y1 = cy - t1; y1 = fminf(fmaxf(y1, 0.f), 800.f);
      t1 = 0.5f * ww; float x1 = cx - t1; x1 = fminf(fmaxf(x1, 0.f), 800.f);
      t1 = 0.5f * hh; float y2 = cy + t1; y2 = fminf(fmaxf(y2, 0.f), 800.f);
      t1 = 0.5f * ww; float x2 = cx + t1; x2 = fminf(fmaxf(x2, 0.f), 800.f);
      bool keep = (y2 - y1 >= 16.f) && (x2 - x1 >= 16.f);
      size_t gi = (size_t)b * NANCH + (size_t)p * 9 + a;
      scores[gi] = keep ? fg : -INFINITY;
      *(float4*)(boxes + gi * 4) = make_float4(y1, x1, y2, x2);
    }
  }
}

// ---------------- anchors output ----------------
__global__ __launch_bounds__(256) void k_anchors(float* __restrict__ out) {
  int i = blockIdx.x * 256 + threadIdx.x;
  if (i < NANCH) {
    int p = i / 9, a = i - p * 9;
    int yy = p / 50, xx = p - yy * 50;
    float y1, x1, y2, x2;
    anchor4(a, yy, xx, y1, x1, y2, x2);
    *(float4*)(out + OUT_ANCH + (size_t)i * 4) = make_float4(y1, x1, y2, x2);
  }
}

// ---------------- radix-select + stable compaction + NMS (f32, proven) ----------------
__global__ __launch_bounds__(1024) void k_nms(
    const float* __restrict__ scores, const float* __restrict__ boxes,
    float* __restrict__ out)
{
#pragma clang fp contract(off)
  const int b = blockIdx.x;
  const float* s = scores + (size_t)b * NANCH;
  const float* bx = boxes + (size_t)b * NANCH * 4;
  const int t = threadIdx.x;
  const int lane = t & 63, wid = t >> 6;
  __shared__ float cscore[6000];
  __shared__ float4 cbox[6000];
  __shared__ unsigned sHist[256];
  __shared__ unsigned sScan[17];
  __shared__ float wred_s[16];
  __shared__ int wred_e[16];
  __shared__ unsigned sPrefix, sKr, sG;
  __shared__ float sWinS;
  __shared__ int sWinE;

  for (int e = t; e < 6000; e += 1024) {
    cscore[e] = -INFINITY;
    cbox[e] = make_float4(0.f, 0.f, 0.f, 0.f);
  }
  if (t == 0) { sPrefix = 0u; sKr = 6000u; sG = 0u; }
  __syncthreads();

  for (int pass = 0; pass < 4; ++pass) {
    const int shift = 24 - 8 * pass;
    if (t < 256) sHist[t] = 0u;
    __syncthreads();
    const unsigned pref = sPrefix;
    const unsigned himask = (pass == 0) ? 0u : (0xFFFFFFFFu << (shift + 8));
    for (int i = t; i < NANCH; i += 1024) {
      unsigned key = keyOf(s[i]);
      if ((key & himask) == pref) atomicAdd(&sHist[(key >> shift) & 255u], 1u);
    }
    __syncthreads();
    if (t == 0) {
      unsigned Kr = sKr, acc = 0; int dsel = 0;
      for (int d = 255; d >= 0; --d) {
        unsigned c = sHist[d];
        if (acc + c >= Kr) { dsel = d; break; }
        acc += c;
      }
      sPrefix = pref | ((unsigned)dsel << shift);
      sKr = Kr - acc;
    }
    __syncthreads();
  }
  const unsigned cut = sPrefix;

  unsigned cg = 0;
  for (int i = t; i < NANCH; i += 1024)
    if (keyOf(s[i]) > cut) cg++;
  atomicAdd(&sG, cg);
  __syncthreads();
  const unsigned Gc = sG;
  const unsigned R = (Gc < 6000u) ? (6000u - Gc) : 0u;

  unsigned run_gt = 0, run_eq = 0;
  for (int chunk = 0; chunk < 22; ++chunk) {
    int i = (chunk << 10) + t;
    float sv = 0.f; unsigned key = 0u;
    if (i < NANCH) { sv = s[i]; key = keyOf(sv); }
    unsigned item = (i < NANCH) ? ((key > cut) ? 0x10000u : ((key == cut) ? 1u : 0u)) : 0u;
    unsigned inc = item;
    #pragma unroll
    for (int d = 1; d < 64; d <<= 1) {
      unsigned n = __shfl_up(inc, d, 64);
      if (lane >= d) inc += n;
    }
    if (lane == 63) sScan[wid] = inc;
    __syncthreads();
    if (t == 0) {
      unsigned a2 = 0;
      for (int k = 0; k < 16; ++k) { unsigned tmp = sScan[k]; sScan[k] = a2; a2 += tmp; }
      sScan[16] = a2;
    }
    __syncthreads();
    unsigned excl = inc - item + sScan[wid];
    unsigned total = sScan[16];
    __syncthreads();
    unsigned gt_b = run_gt + (excl >> 16);
    unsigned eq_b = run_eq + (excl & 0xFFFFu);
    bool sel = ((item >> 16) != 0u) || (((item & 0xFFFFu) != 0u) && (eq_b < R));
    if (sel) {
      unsigned pos = gt_b + (eq_b < R ? eq_b : R);
      if (pos < 6000u) {
        cscore[pos] = sv;
        cbox[pos] = *(const float4*)(bx + (size_t)i * 4);
      }
    }
    run_gt += (total >> 16); run_eq += (total & 0xFFFFu);
  }
  __syncthreads();

  float sreg[6]; float4 breg[6];
  #pragma unroll
  for (int j = 0; j < 6; ++j) {
    int e = t + (j << 10);
    if (e < 6000) {
      sreg[j] = cscore[e];
      breg[j] = cbox[e];
    } else {
      sreg[j] = -INFINITY;
      breg[j] = make_float4(0.f, 0.f, 0.f, 0.f);
    }
  }
  __syncthreads();

  for (int it = 0; it < 300; ++it) {
    float bs = sreg[0]; int be = t;
    #pragma unroll
    for (int j = 1; j < 6; ++j) {
      if (sreg[j] > bs) { bs = sreg[j]; be = t + (j << 10); }
    }
    #pragma unroll
    for (int d = 1; d < 64; d <<= 1) {
      float os = __shfl_xor(bs, d);
      int oe = __shfl_xor(be, d);
      if (os > bs || (os == bs && oe < be)) { bs = os; be = oe; }
    }
    if (lane == 0) { wred_s[wid] = bs; wred_e[wid] = be; }
    __syncthreads();
    if (t == 0) {
      float ws0 = wred_s[0]; int we0 = wred_e[0];
      for (int k = 1; k < 16; ++k) {
        float s2 = wred_s[k]; int e2 = wred_e[k];
        if (s2 > ws0 || (s2 == ws0 && e2 < we0)) { ws0 = s2; we0 = e2; }
      }
      sWinS = ws0; sWinE = we0;
    }
    __syncthreads();
    const float wsc = sWinS; const int we = sWinE;
    const float4 wb = cbox[we];
    const bool valid = (wsc > -INFINITY);
    if (t == 0) {
      const float m = valid ? 1.f : 0.f;
      size_t ro = OUT_ROIS + ((size_t)b * 300 + it) * 4;
      out[ro + 0] = wb.x * m; out[ro + 1] = wb.y * m;
      out[ro + 2] = wb.z * m; out[ro + 3] = wb.w * m;
      out[OUT_ROIID + (size_t)b * 300 + it] = valid ? (float)b : 0.f;
    }
    {
      const float a1 = (wb.z - wb.x) * (wb.w - wb.y);
      #pragma unroll
      for (int j = 0; j < 6; ++j) {
        float ty1 = fmaxf(wb.x, breg[j].x);
        float tx1 = fmaxf(wb.y, breg[j].y);
        float ty2 = fminf(wb.z, breg[j].z);
        float tx2 = fminf(wb.w, breg[j].w);
        float inter = fmaxf(ty2 - ty1, 0.f) * fmaxf(tx2 - tx1, 0.f);
        float a2 = (breg[j].z - breg[j].x) * (breg[j].w - breg[j].y);
        float ov = inter / (a1 + a2 - inter + 1e-9f);
        if (ov > 0.7f) sreg[j] = -INFINITY;
      }
    }
    __syncthreads();
  }
}

extern "C" void kernel_launch(void* const* d_in, const int* in_sizes, int n_in,
                              void* d_out, int out_size, void* d_ws, size_t ws_size,
                              hipStream_t stream) {
  (void)in_sizes; (void)n_in; (void)out_size;
  // ws: sh 10.24M f64 (81.92MB) | scores 180K f32 | boxes 720K f32
  const size_t need = (size_t)10240000 * 8 + (size_t)(180000 + 720000) * 4;
  if (ws_size < need) return;
  const float* x   = (const float*)d_in[0];
  const float* Wsh = (const float*)d_in[1];
  const float* bsh = (const float*)d_in[2];
  const float* Wc  = (const float*)d_in[3];
  const float* bc  = (const float*)d_in[4];
  const float* Wr  = (const float*)d_in[5];
  const float* br  = (const float*)d_in[6];
  float* out = (float*)d_out;
  double* sh = (double*)d_ws;
  float* scores = (float*)(sh + 10240000);
  float* boxes  = scores + 180000;

  hipLaunchKernelGGL(k_conv3x3, dim3(20, 8, 8), dim3(256), 0, stream, x, Wsh, bsh, sh);
  hipLaunchKernelGGL(k_heads,   dim3(40, 8),    dim3(256), 0, stream, sh, Wc, bc, Wr, br, out, scores, boxes);
  hipLaunchKernelGGL(k_anchors, dim3(88),       dim3(256), 0, stream, out);
  hipLaunchKernelGGL(k_nms,     dim3(8),        dim3(1024), 0, stream, scores, boxes, out);
}